// Round 1
// baseline (6010.124 us; speedup 1.0000x reference)
//
#include <hip/hip_runtime.h>
#include <hip/hip_bf16.h>

// Problem constants
#define LL 512
#define BB 64
#define DD 512
#define HH 1024
#define NWG 64   // recurrent workgroups; each owns 16 rows of Wh

typedef __bf16 bf16x8 __attribute__((ext_vector_type(8)));
typedef float f32x4 __attribute__((ext_vector_type(4)));

// fp32 -> bf16 round-to-nearest-even (finite inputs only)
static __device__ __forceinline__ unsigned short f2bf_u(float f) {
  unsigned u = __builtin_bit_cast(unsigned, f);
  u += 0x7fffu + ((u >> 16) & 1u);
  return (unsigned short)(u >> 16);
}
static __device__ __forceinline__ float bfu2f(unsigned u) {
  u <<= 16;
  return __builtin_bit_cast(float, u);
}

// ---------------------------------------------------------------------------
// Kernel 1: xproj[l][b][h] = sum_d x[b][l][d] * Wx[h][d]   (bias folded later)
// M = L*B = 32768 (m = l*64+b), N = H = 1024, K = D = 512. bf16 MFMA,
// 128x128x32 tiles, double-buffered LDS, XOR swizzle, reg-staged fp32->bf16.
// ---------------------------------------------------------------------------
__global__ __launch_bounds__(256) void xproj_gemm(
    const float* __restrict__ x, const float* __restrict__ Wx,
    unsigned short* __restrict__ xp) {
  __shared__ unsigned short As[2][128 * 32];
  __shared__ unsigned short Bs[2][128 * 32];
  const int tid = threadIdx.x;
  const int lane = tid & 63, wid = tid >> 6;
  const int mt = blockIdx.x, nt = blockIdx.y;
  const int wm = (wid >> 1) * 64, wn = (wid & 1) * 64;

  // staging: thread -> (row, 16-col chunk)
  const int srow = tid >> 1, skq = (tid & 1) * 16;
  const int mrow = mt * 128 + srow;  // m = l*64 + b
  const float* aSrc =
      x + (size_t)(mrow & 63) * (LL * DD) + (size_t)(mrow >> 6) * DD + skq;
  const float* bSrc = Wx + (size_t)(nt * 128 + srow) * DD + skq;
  const int wbyte = srow * 64 + skq * 2;
  const int wswz = (srow & 7) << 4;

  f32x4 acc[4][4] = {};
  const int fr = lane & 15, fo = lane >> 4;

#define STAGE(buf, k0, src, dst)                                    \
  {                                                                 \
    float4 f0 = *(const float4*)((src) + (k0));                     \
    float4 f1 = *(const float4*)((src) + (k0) + 4);                 \
    float4 f2 = *(const float4*)((src) + (k0) + 8);                 \
    float4 f3 = *(const float4*)((src) + (k0) + 12);                \
    uint4 p0, p1;                                                   \
    p0.x = f2bf_u(f0.x) | ((unsigned)f2bf_u(f0.y) << 16);           \
    p0.y = f2bf_u(f0.z) | ((unsigned)f2bf_u(f0.w) << 16);           \
    p0.z = f2bf_u(f1.x) | ((unsigned)f2bf_u(f1.y) << 16);           \
    p0.w = f2bf_u(f1.z) | ((unsigned)f2bf_u(f1.w) << 16);           \
    p1.x = f2bf_u(f2.x) | ((unsigned)f2bf_u(f2.y) << 16);           \
    p1.y = f2bf_u(f2.z) | ((unsigned)f2bf_u(f2.w) << 16);           \
    p1.z = f2bf_u(f3.x) | ((unsigned)f2bf_u(f3.y) << 16);           \
    p1.w = f2bf_u(f3.z) | ((unsigned)f2bf_u(f3.w) << 16);           \
    char* bp = (char*)(dst)[buf];                                   \
    *(uint4*)(bp + ((wbyte) ^ wswz)) = p0;                          \
    *(uint4*)(bp + ((wbyte + 16) ^ wswz)) = p1;                     \
  }

  STAGE(0, 0, aSrc, As)
  STAGE(0, 0, bSrc, Bs)
  __syncthreads();

  for (int ks = 0; ks < 16; ++ks) {
    const int cur = ks & 1;
    if (ks < 15) {
      STAGE(cur ^ 1, (ks + 1) * 32, aSrc, As)
      STAGE(cur ^ 1, (ks + 1) * 32, bSrc, Bs)
    }
    const char* ab = (const char*)As[cur];
    const char* bb = (const char*)Bs[cur];
    bf16x8 af[4], bfr[4];
#pragma unroll
    for (int i = 0; i < 4; ++i) {
      int ra = wm + i * 16 + fr;
      af[i] = *(const bf16x8*)(ab + ((ra * 64 + fo * 16) ^ ((ra & 7) << 4)));
      int rb = wn + i * 16 + fr;
      bfr[i] = *(const bf16x8*)(bb + ((rb * 64 + fo * 16) ^ ((rb & 7) << 4)));
    }
#pragma unroll
    for (int i = 0; i < 4; ++i)
#pragma unroll
      for (int j = 0; j < 4; ++j)
        acc[i][j] = __builtin_amdgcn_mfma_f32_16x16x32_bf16(af[i], bfr[j],
                                                            acc[i][j], 0, 0, 0);
    __syncthreads();
  }
#undef STAGE

  // epilogue: C row=(lane>>4)*4+q (m), col=lane&15 (h). xp index = m*H + h.
#pragma unroll
  for (int i = 0; i < 4; ++i) {
#pragma unroll
    for (int j = 0; j < 4; ++j) {
      int hh = nt * 128 + wn + j * 16 + fr;
#pragma unroll
      for (int q = 0; q < 4; ++q) {
        int mg = mt * 128 + wm + i * 16 + fo * 4 + q;
        xp[(size_t)mg * HH + hh] = f2bf_u(acc[i][j][q]);
      }
    }
  }
}

// ---------------------------------------------------------------------------
// Kernel 2: persistent recurrence. 64 WGs x 256 thr. WG wg owns j-slice
// [wg*16, wg*16+16) of H. Wh slice lives in LDS (bf16, swizzled) for all 512
// steps. h double-buffered in global (bf16). c in registers. Custom grid
// barrier per step.
// ---------------------------------------------------------------------------
__global__ __launch_bounds__(256) void rnn_recur(
    const float* __restrict__ Wh_w, const float* __restrict__ Wh_b,
    const float* __restrict__ Wx_b, const float* __restrict__ Wa_w,
    const unsigned short* __restrict__ xp, unsigned short* __restrict__ hb0,
    unsigned short* __restrict__ hb1, float* __restrict__ y_pre,
    int* __restrict__ bar) {
  __shared__ unsigned short WhS[16 * 1024];  // 32 KiB
  const int wg = blockIdx.x;
  const int tid = threadIdx.x;
  const int lane = tid & 63, wid = tid >> 6;

  // One-time: Wh rows [wg*16, +16) -> LDS bf16, XOR-swizzled rows.
  for (int i = tid; i < 16 * 1024; i += 256) {
    int r = i >> 10, k = i & 1023;
    unsigned short v = f2bf_u(Wh_w[(size_t)(wg * 16 + r) * HH + k]);
    int byte = (r * 2048 + k * 2) ^ ((r & 7) << 4);
    *(unsigned short*)((char*)WhS + byte) = v;
  }

  const int b = wid * 16 + (lane & 15);   // batch row this lane covers (B-col)
  const int jq = (lane >> 4) * 4;         // local j of C rows
  const int jbase = wg * 16 + jq;
  float bias[4], wa0[4], wa1[4];
#pragma unroll
  for (int q = 0; q < 4; ++q) {
    bias[q] = Wh_b[jbase + q] + Wx_b[jbase + q];
    wa0[q] = Wa_w[jbase + q];
    wa1[q] = Wa_w[HH + jbase + q];
  }
  float c4[4] = {0.f, 0.f, 0.f, 0.f};
  const int ar = lane & 15;           // A-frag row (j_local)
  const int aswz = (ar & 7) << 4;
  const int koct = (lane >> 4) * 8;   // k octet
  const char* whb = (const char*)WhS;
  __syncthreads();

#pragma unroll 1
  for (int l = 0; l < LL; ++l) {
    const unsigned short* hcur = (l & 1) ? hb1 : hb0;
    unsigned short* hnext = (l & 1) ? hb0 : hb1;
    const unsigned short* hrow = hcur + (size_t)b * HH;

    uint2 xpu = *(const uint2*)(xp + ((size_t)l * BB + b) * HH + jbase);

    f32x4 a0 = {0, 0, 0, 0}, a1 = {0, 0, 0, 0};
    f32x4 a2 = {0, 0, 0, 0}, a3 = {0, 0, 0, 0};
#pragma unroll
    for (int kk = 0; kk < 32; ++kk) {
      const int k0 = kk * 32 + koct;
      bf16x8 av = *(const bf16x8*)(whb + ((ar * 2048 + k0 * 2) ^ aswz));
      bf16x8 hv8 = *(const bf16x8*)(hrow + k0);
      if ((kk & 3) == 0)
        a0 = __builtin_amdgcn_mfma_f32_16x16x32_bf16(av, hv8, a0, 0, 0, 0);
      else if ((kk & 3) == 1)
        a1 = __builtin_amdgcn_mfma_f32_16x16x32_bf16(av, hv8, a1, 0, 0, 0);
      else if ((kk & 3) == 2)
        a2 = __builtin_amdgcn_mfma_f32_16x16x32_bf16(av, hv8, a2, 0, 0, 0);
      else
        a3 = __builtin_amdgcn_mfma_f32_16x16x32_bf16(av, hv8, a3, 0, 0, 0);
    }
    f32x4 asum = (a0 + a1) + (a2 + a3);

    float xa[4] = {bfu2f(xpu.x & 0xffffu), bfu2f(xpu.x >> 16),
                   bfu2f(xpu.y & 0xffffu), bfu2f(xpu.y >> 16)};
    float hv[4];
    unsigned short hp[4];
#pragma unroll
    for (int q = 0; q < 4; ++q) {
      float a = asum[q] + bias[q] + xa[q];
      a = fminf(30.f, fmaxf(-30.f, a));
      float E = __expf(-a);          // e^-a
      float s = 1.f / (1.f + E);     // sigmoid(a)
      float E2 = E * E;              // e^-2a
      float g = (1.f - E2) / (1.f + E2);  // tanh(a)
      float c = s * (c4[q] + g);
      c4[q] = c;
      float ccl = fminf(15.f, fmaxf(-15.f, c));
      float F = __expf(-2.f * ccl);
      float th = (1.f - F) / (1.f + F);  // tanh(c)
      hv[q] = s * th;
      hp[q] = f2bf_u(hv[q]);
    }
    uint2 hu;
    hu.x = (unsigned)hp[0] | ((unsigned)hp[1] << 16);
    hu.y = (unsigned)hp[2] | ((unsigned)hp[3] << 16);
    *(uint2*)(hnext + (size_t)b * HH + jbase) = hu;

    // y partial: this WG's j-slice contribution, fp32 h. Reduce over the 4
    // jq-groups (lanes x, x^16, x^32, x^48 share the same b).
    float py0 = wa0[0] * hv[0] + wa0[1] * hv[1] + wa0[2] * hv[2] + wa0[3] * hv[3];
    float py1 = wa1[0] * hv[0] + wa1[1] * hv[1] + wa1[2] * hv[2] + wa1[3] * hv[3];
    py0 += __shfl_xor(py0, 16);
    py0 += __shfl_xor(py0, 32);
    py1 += __shfl_xor(py1, 16);
    py1 += __shfl_xor(py1, 32);
    if (lane < 32) {
      int o = lane >> 4;
      float v = o ? py1 : py0;
      int bo = wid * 16 + (lane & 15);
      // layout [b][o][l]: 128 distinct cache lines per step -> no line serialization
      atomicAdd(&y_pre[((size_t)bo * 2 + o) * LL + l], v);
    }

    if (l != LL - 1) {
      // device-wide sense barrier
      __syncthreads();
      if (tid == 0) {
        __threadfence();  // release: drain + make h/y stores device-visible
        int gen = __hip_atomic_load(&bar[1], __ATOMIC_RELAXED,
                                    __HIP_MEMORY_SCOPE_AGENT);
        int old = __hip_atomic_fetch_add(&bar[0], 1, __ATOMIC_ACQ_REL,
                                         __HIP_MEMORY_SCOPE_AGENT);
        if (old == NWG - 1) {
          __hip_atomic_store(&bar[0], 0, __ATOMIC_RELAXED,
                             __HIP_MEMORY_SCOPE_AGENT);
          __hip_atomic_store(&bar[1], gen + 1, __ATOMIC_RELEASE,
                             __HIP_MEMORY_SCOPE_AGENT);
        } else {
          while (__hip_atomic_load(&bar[1], __ATOMIC_RELAXED,
                                   __HIP_MEMORY_SCOPE_AGENT) == gen) {
            __builtin_amdgcn_s_sleep(1);
          }
        }
        __threadfence();  // acquire: invalidate stale L1/L2 before next reads
      }
      __syncthreads();
    }
  }
}

// ---------------------------------------------------------------------------
// Kernel 3: out[b][l][o] = sigmoid(y_pre[b][o][l] + Wa_b[o])
// ---------------------------------------------------------------------------
__global__ __launch_bounds__(256) void y_final(const float* __restrict__ y_pre,
                                               const float* __restrict__ Wa_b,
                                               float* __restrict__ out) {
  int idx = blockIdx.x * 256 + threadIdx.x;
  if (idx >= BB * LL * 2) return;
  int b = idx >> 10, rem = idx & 1023;
  int l = rem >> 1, o = rem & 1;
  float v = y_pre[((size_t)b * 2 + o) * LL + l] + Wa_b[o];
  out[idx] = 1.f / (1.f + __expf(-v));
}

// ---------------------------------------------------------------------------
extern "C" void kernel_launch(void* const* d_in, const int* in_sizes, int n_in,
                              void* d_out, int out_size, void* d_ws,
                              size_t ws_size, hipStream_t stream) {
  const float* x = (const float*)d_in[0];
  const float* Wh_w = (const float*)d_in[1];
  const float* Wh_b = (const float*)d_in[2];
  const float* Wx_w = (const float*)d_in[3];
  const float* Wx_b = (const float*)d_in[4];
  const float* Wa_w = (const float*)d_in[5];
  const float* Wa_b = (const float*)d_in[6];
  float* out = (float*)d_out;

  char* ws = (char*)d_ws;
  unsigned short* xp = (unsigned short*)ws;                 // 67,108,864 B
  unsigned short* hb0 = (unsigned short*)(ws + 67108864);   // 131,072 B
  unsigned short* hb1 = (unsigned short*)(ws + 67108864 + 131072);  // 131,072 B
  float* y_pre = (float*)(ws + 67108864 + 262144);          // 262,144 B
  int* bar = (int*)(ws + 67108864 + 262144 + 262144);       // barrier state

  // zero h0, h1, y_pre, barrier (ws is poisoned 0xAA before every call)
  hipMemsetAsync(ws + 67108864, 0, 262144 + 262144 + 256, stream);

  dim3 g1(256, 8);
  xproj_gemm<<<g1, 256, 0, stream>>>(x, Wx_w, xp);
  rnn_recur<<<NWG, 256, 0, stream>>>(Wh_w, Wh_b, Wx_b, Wa_w, xp, hb0, hb1,
                                     y_pre, bar);
  y_final<<<256, 256, 0, stream>>>(y_pre, Wa_b, out);
}

// Round 3
// 3440.276 us; speedup vs baseline: 1.7470x; 1.7470x over previous
//
#include <hip/hip_runtime.h>
#include <hip/hip_bf16.h>

// Problem constants
#define LL 512
#define BB 64
#define DD 512
#define HH 1024
#define NWG 64   // recurrent workgroups; each owns 16 rows of Wh

typedef __bf16 bf16x8 __attribute__((ext_vector_type(8)));
typedef float f32x4 __attribute__((ext_vector_type(4)));

// fp32 -> bf16 round-to-nearest-even (finite inputs only)
static __device__ __forceinline__ unsigned short f2bf_u(float f) {
  unsigned u = __builtin_bit_cast(unsigned, f);
  u += 0x7fffu + ((u >> 16) & 1u);
  return (unsigned short)(u >> 16);
}
static __device__ __forceinline__ float bfu2f(unsigned u) {
  u <<= 16;
  return __builtin_bit_cast(float, u);
}

// ---------------------------------------------------------------------------
// Kernel 1: xproj = x . Wx^T, written in layout [l][hblk16][b][hloc16] (bf16)
// so each recurrent WG reads a contiguous 2KB block per step.
// M = L*B = 32768 (m = l*64+b), N = H = 1024, K = D = 512. bf16 MFMA,
// 128x128x32 tiles, double-buffered LDS, XOR swizzle, reg-staged fp32->bf16.
// ---------------------------------------------------------------------------
__global__ __launch_bounds__(256) void xproj_gemm(
    const float* __restrict__ x, const float* __restrict__ Wx,
    unsigned short* __restrict__ xp) {
  __shared__ unsigned short As[2][128 * 32];
  __shared__ unsigned short Bs[2][128 * 32];
  const int tid = threadIdx.x;
  const int lane = tid & 63, wid = tid >> 6;
  const int mt = blockIdx.x, nt = blockIdx.y;
  const int wm = (wid >> 1) * 64, wn = (wid & 1) * 64;

  // staging: thread -> (row, 16-col chunk)
  const int srow = tid >> 1, skq = (tid & 1) * 16;
  const int mrow = mt * 128 + srow;  // m = l*64 + b
  const float* aSrc =
      x + (size_t)(mrow & 63) * (LL * DD) + (size_t)(mrow >> 6) * DD + skq;
  const float* bSrc = Wx + (size_t)(nt * 128 + srow) * DD + skq;
  const int wbyte = srow * 64 + skq * 2;
  const int wswz = (srow & 7) << 4;

  f32x4 acc[4][4] = {};
  const int fr = lane & 15, fo = lane >> 4;

#define STAGE(buf, k0, src, dst)                                    \
  {                                                                 \
    float4 f0 = *(const float4*)((src) + (k0));                     \
    float4 f1 = *(const float4*)((src) + (k0) + 4);                 \
    float4 f2 = *(const float4*)((src) + (k0) + 8);                 \
    float4 f3 = *(const float4*)((src) + (k0) + 12);                \
    uint4 p0, p1;                                                   \
    p0.x = f2bf_u(f0.x) | ((unsigned)f2bf_u(f0.y) << 16);           \
    p0.y = f2bf_u(f0.z) | ((unsigned)f2bf_u(f0.w) << 16);           \
    p0.z = f2bf_u(f1.x) | ((unsigned)f2bf_u(f1.y) << 16);           \
    p0.w = f2bf_u(f1.z) | ((unsigned)f2bf_u(f1.w) << 16);           \
    p1.x = f2bf_u(f2.x) | ((unsigned)f2bf_u(f2.y) << 16);           \
    p1.y = f2bf_u(f2.z) | ((unsigned)f2bf_u(f2.w) << 16);           \
    p1.z = f2bf_u(f3.x) | ((unsigned)f2bf_u(f3.y) << 16);           \
    p1.w = f2bf_u(f3.z) | ((unsigned)f2bf_u(f3.w) << 16);           \
    char* bp = (char*)(dst)[buf];                                   \
    *(uint4*)(bp + ((wbyte) ^ wswz)) = p0;                          \
    *(uint4*)(bp + ((wbyte + 16) ^ wswz)) = p1;                     \
  }

  STAGE(0, 0, aSrc, As)
  STAGE(0, 0, bSrc, Bs)
  __syncthreads();

  for (int ks = 0; ks < 16; ++ks) {
    const int cur = ks & 1;
    if (ks < 15) {
      STAGE(cur ^ 1, (ks + 1) * 32, aSrc, As)
      STAGE(cur ^ 1, (ks + 1) * 32, bSrc, Bs)
    }
    const char* ab = (const char*)As[cur];
    const char* bb = (const char*)Bs[cur];
    bf16x8 af[4], bfr[4];
#pragma unroll
    for (int i = 0; i < 4; ++i) {
      int ra = wm + i * 16 + fr;
      af[i] = *(const bf16x8*)(ab + ((ra * 64 + fo * 16) ^ ((ra & 7) << 4)));
      int rb = wn + i * 16 + fr;
      bfr[i] = *(const bf16x8*)(bb + ((rb * 64 + fo * 16) ^ ((rb & 7) << 4)));
    }
#pragma unroll
    for (int i = 0; i < 4; ++i)
#pragma unroll
      for (int j = 0; j < 4; ++j)
        acc[i][j] = __builtin_amdgcn_mfma_f32_16x16x32_bf16(af[i], bfr[j],
                                                            acc[i][j], 0, 0, 0);
    __syncthreads();
  }
#undef STAGE

  // epilogue: C row=(lane>>4)*4+q (m), col=lane&15 (h).
  // xp idx = l*65536 + (h>>4)*1024 + b*16 + (h&15); l=m>>6, b=m&63.
#pragma unroll
  for (int i = 0; i < 4; ++i) {
#pragma unroll
    for (int j = 0; j < 4; ++j) {
      int hh = nt * 128 + wn + j * 16 + fr;
#pragma unroll
      for (int q = 0; q < 4; ++q) {
        int mg = mt * 128 + wm + i * 16 + fo * 4 + q;
        size_t idx = (size_t)(mg >> 6) * 65536 + (size_t)(hh >> 4) * 1024 +
                     (mg & 63) * 16 + (hh & 15);
        xp[idx] = f2bf_u(acc[i][j][q]);
      }
    }
  }
}

// ---------------------------------------------------------------------------
// Kernel 2: persistent recurrence. 64 WGs x 256 thr. WG wg owns j-slice
// [wg*16, wg*16+16). Wh frags live in REGISTERS (128 VGPR/lane). h double-
// buffered in global bf16, accessed with sc0 sc1 (LLC-coherent, no fences).
// Per-step arrival counters cnt[l] replace the sense barrier.
// ---------------------------------------------------------------------------
__global__ __launch_bounds__(256, 1) void rnn_recur(
    const float* __restrict__ Wh_w, const float* __restrict__ Wh_b,
    const float* __restrict__ Wx_b, const float* __restrict__ Wa_w,
    const unsigned short* __restrict__ xp, unsigned short* __restrict__ hb0,
    unsigned short* __restrict__ hb1, float* __restrict__ y_pre,
    int* __restrict__ cnt) {
  const int wg = blockIdx.x;
  const int tid = threadIdx.x;
  const int lane = tid & 63, wid = tid >> 6;

  const int ar = lane & 15;          // A-frag row = local j
  const int koct = (lane >> 4) * 8;  // k octet base
  const int b = wid * 16 + ar;       // B-frag col = batch row
  const int jq = (lane >> 4) * 4;    // C rows (local j) this lane holds
  const int jbase = wg * 16 + jq;

  // One-time: Wh fragment registers. lane (ar, koct) holds rows wg*16+ar,
  // k = kk*32 + koct .. +8 for kk = 0..31.  32 x bf16x8 = 128 VGPR.
  bf16x8 whf[32];
#pragma unroll
  for (int kk = 0; kk < 32; ++kk) {
    const float* s = Wh_w + (size_t)(wg * 16 + ar) * HH + kk * 32 + koct;
    float4 f0 = *(const float4*)s;
    float4 f1 = *(const float4*)(s + 4);
    union { unsigned short u[8]; bf16x8 v; } t;
    t.u[0] = f2bf_u(f0.x); t.u[1] = f2bf_u(f0.y);
    t.u[2] = f2bf_u(f0.z); t.u[3] = f2bf_u(f0.w);
    t.u[4] = f2bf_u(f1.x); t.u[5] = f2bf_u(f1.y);
    t.u[6] = f2bf_u(f1.z); t.u[7] = f2bf_u(f1.w);
    whf[kk] = t.v;
  }

  float bias[4], wa0[4], wa1[4];
#pragma unroll
  for (int q = 0; q < 4; ++q) {
    bias[q] = Wh_b[jbase + q] + Wx_b[jbase + q];
    wa0[q] = Wa_w[jbase + q];
    wa1[q] = Wa_w[HH + jbase + q];
  }
  float c4[4] = {0.f, 0.f, 0.f, 0.f};

#pragma unroll 1
  for (int l = 0; l < LL; ++l) {
    const unsigned short* hrow = ((l & 1) ? hb1 : hb0) + (size_t)b * HH;
    unsigned short* hst = ((l & 1) ? hb0 : hb1) + (size_t)b * HH + jbase;

    // xp for this step: contiguous [l][wg][b][16] layout, 8B per lane.
    // Issued FIRST (oldest in vmcnt FIFO); retired by the vmcnt(24) wait.
    uint2 xpu;
    asm volatile("global_load_dwordx2 %0, %1, off"
                 : "=v"(xpu)
                 : "v"(xp + (size_t)l * (BB * HH) + wg * 1024 + b * 16 + jq));

    // Issue ALL h loads (32 x 16B, LLC-coherent). 33 vmem ops in flight.
    uint4 hbuf[4][8];
#pragma unroll
    for (int c = 0; c < 4; ++c)
#pragma unroll
      for (int i = 0; i < 8; ++i)
        asm volatile("global_load_dwordx4 %0, %1, off sc0 sc1"
                     : "=v"(hbuf[c][i])
                     : "v"(hrow + (c * 8 + i) * 32 + koct));

    f32x4 acc4[4] = {};

#define MFMA_CHUNK(c)                                                        \
  _Pragma("unroll") for (int i = 0; i < 8; ++i) {                            \
    acc4[i & 3] = __builtin_amdgcn_mfma_f32_16x16x32_bf16(                   \
        whf[(c) * 8 + i], __builtin_bit_cast(bf16x8, hbuf[c][i]),            \
        acc4[i & 3], 0, 0, 0);                                               \
  }

    asm volatile("s_waitcnt vmcnt(24)" ::: "memory");  // xp + chunk0 done
    __builtin_amdgcn_sched_barrier(0);
    MFMA_CHUNK(0)
    asm volatile("s_waitcnt vmcnt(16)" ::: "memory");  // chunk1 done
    __builtin_amdgcn_sched_barrier(0);
    MFMA_CHUNK(1)
    asm volatile("s_waitcnt vmcnt(8)" ::: "memory");   // chunk2 done
    __builtin_amdgcn_sched_barrier(0);
    MFMA_CHUNK(2)
    asm volatile("s_waitcnt vmcnt(0)" ::: "memory");   // chunk3 done
    __builtin_amdgcn_sched_barrier(0);
    MFMA_CHUNK(3)
#undef MFMA_CHUNK

    f32x4 asum = (acc4[0] + acc4[1]) + (acc4[2] + acc4[3]);
    float xa[4] = {bfu2f(xpu.x & 0xffffu), bfu2f(xpu.x >> 16),
                   bfu2f(xpu.y & 0xffffu), bfu2f(xpu.y >> 16)};
    float hv[4];
    unsigned short hp[4];
#pragma unroll
    for (int q = 0; q < 4; ++q) {
      float a = asum[q] + bias[q] + xa[q];
      a = fminf(30.f, fmaxf(-30.f, a));
      float E = __expf(-a);               // e^-a
      float s = 1.f / (1.f + E);          // sigmoid(a)
      float E2 = E * E;                   // e^-2a
      float g = (1.f - E2) / (1.f + E2);  // tanh(a)
      float c = s * (c4[q] + g);
      c4[q] = c;
      float ccl = fminf(15.f, fmaxf(-15.f, c));
      float F = __expf(-2.f * ccl);
      float th = (1.f - F) / (1.f + F);   // tanh(c)
      hv[q] = s * th;
      hp[q] = f2bf_u(hv[q]);
    }
    uint2 hu;
    hu.x = (unsigned)hp[0] | ((unsigned)hp[1] << 16);
    hu.y = (unsigned)hp[2] | ((unsigned)hp[3] << 16);
    // write-through to LLC
    asm volatile("global_store_dwordx2 %0, %1, off sc0 sc1" ::"v"(hst),
                 "v"(hu)
                 : "memory");

    // y partials (DS/VALU only — overlaps the store drain)
    float py0 =
        wa0[0] * hv[0] + wa0[1] * hv[1] + wa0[2] * hv[2] + wa0[3] * hv[3];
    float py1 =
        wa1[0] * hv[0] + wa1[1] * hv[1] + wa1[2] * hv[2] + wa1[3] * hv[3];
    py0 += __shfl_xor(py0, 16);
    py0 += __shfl_xor(py0, 32);
    py1 += __shfl_xor(py1, 16);
    py1 += __shfl_xor(py1, 32);

    // drain h store to LLC, then arrive
    asm volatile("s_waitcnt vmcnt(0)" ::: "memory");
    __syncthreads();
    if (tid == 32)
      __hip_atomic_fetch_add(&cnt[l], 1, __ATOMIC_RELAXED,
                             __HIP_MEMORY_SCOPE_AGENT);
    // y atomics in the barrier slack (tid 32 polls; it does no y-atomic)
    if (lane < 32) {
      int o = lane >> 4;
      float v = o ? py1 : py0;
      int bo = wid * 16 + (lane & 15);
      atomicAdd(&y_pre[((size_t)bo * 2 + o) * LL + l], v);
    }
    if (l != LL - 1) {
      if (tid == 32) {
        while (__hip_atomic_load(&cnt[l], __ATOMIC_RELAXED,
                                 __HIP_MEMORY_SCOPE_AGENT) < NWG)
          __builtin_amdgcn_s_sleep(2);
      }
      __syncthreads();
    }
  }
}

// ---------------------------------------------------------------------------
// Kernel 3: out[b][l][o] = sigmoid(y_pre[b][o][l] + Wa_b[o])
// ---------------------------------------------------------------------------
__global__ __launch_bounds__(256) void y_final(const float* __restrict__ y_pre,
                                               const float* __restrict__ Wa_b,
                                               float* __restrict__ out) {
  int idx = blockIdx.x * 256 + threadIdx.x;
  if (idx >= BB * LL * 2) return;
  int b = idx >> 10, rem = idx & 1023;
  int l = rem >> 1, o = rem & 1;
  float v = y_pre[((size_t)b * 2 + o) * LL + l] + Wa_b[o];
  out[idx] = 1.f / (1.f + __expf(-v));
}

// ---------------------------------------------------------------------------
extern "C" void kernel_launch(void* const* d_in, const int* in_sizes, int n_in,
                              void* d_out, int out_size, void* d_ws,
                              size_t ws_size, hipStream_t stream) {
  const float* x = (const float*)d_in[0];
  const float* Wh_w = (const float*)d_in[1];
  const float* Wh_b = (const float*)d_in[2];
  const float* Wx_w = (const float*)d_in[3];
  const float* Wx_b = (const float*)d_in[4];
  const float* Wa_w = (const float*)d_in[5];
  const float* Wa_b = (const float*)d_in[6];
  float* out = (float*)d_out;

  char* ws = (char*)d_ws;
  unsigned short* xp = (unsigned short*)ws;                        // 67,108,864 B
  unsigned short* hb0 = (unsigned short*)(ws + 67108864);          // 131,072 B
  unsigned short* hb1 = (unsigned short*)(ws + 67108864 + 131072); // 131,072 B
  float* y_pre = (float*)(ws + 67371008);                          // 262,144 B
  int* cnt = (int*)(ws + 67633152);                                // 2,048 B

  // zero hb0, hb1, y_pre, cnt (ws is poisoned 0xAA before every call)
  hipMemsetAsync(ws + 67108864, 0, 131072 + 131072 + 262144 + 2048, stream);

  dim3 g1(256, 8);
  xproj_gemm<<<g1, 256, 0, stream>>>(x, Wx_w, xp);
  rnn_recur<<<NWG, 256, 0, stream>>>(Wh_w, Wh_b, Wx_b, Wa_w, xp, hb0, hb1,
                                     y_pre, cnt);
  y_final<<<256, 256, 0, stream>>>(y_pre, Wa_b, out);
}